// Round 15
// baseline (524.733 us; speedup 1.0000x reference)
//
#include <hip/hip_runtime.h>
#include <hip/hip_bf16.h>

typedef __hip_bfloat16 bf16;
typedef __attribute__((ext_vector_type(8))) __bf16 bf16x8;
typedef __attribute__((ext_vector_type(4))) float f32x4;

#define B_ 16384
#define D_ 1024
#define H_ 512
#define O_ 256
#define E_ 8
#define BC_ 8192   // B-chunk rows

static_assert(B_ % BC_ == 0, "chunking");

// async global->LDS, 16B per lane (m97/m201 staging path).
#define GLDS(src, dst) __builtin_amdgcn_global_load_lds( \
    (const __attribute__((address_space(1))) void*)(src), \
    (__attribute__((address_space(3))) void*)(dst), 16, 0, 0)

#define BAR()   asm volatile("s_barrier" ::: "memory")
#define LGKM0() do { asm volatile("s_waitcnt lgkmcnt(0)" ::: "memory"); \
                     __builtin_amdgcn_sched_barrier(0); } while (0)

// ---------------------------------------------------------------------------
// Input-dtype detector (DEVICE-side; in_sizes are ELEMENT counts, dtype-blind
// on host -- round-5 lesson). flag=1 => inputs are fp32.
// ---------------------------------------------------------------------------
__global__ void detect_k(const unsigned short* __restrict__ x, int* __restrict__ flag) {
    __shared__ int s;
    if (threadIdx.x == 0) s = 0;
    __syncthreads();
    int big = 0;
    for (int i = threadIdx.x; i < 2048; i += 256)
        if (((x[i] >> 7) & 0xFF) >= 150) big = 1;
    if (big) atomicOr(&s, 1);
    __syncthreads();
    if (threadIdx.x == 0) *flag = s;
}

// ---------------------------------------------------------------------------
// ALL preprocessing in ONE launch (round-8..14 verified).
//   blocks [0,1024)      : x canonicalize (vectorized)
//   blocks [1024,1031)   : 7 small bias/weight converts
//   blocks [1031,8487)   : 5 weight transposes, in [Z][R][C] ->
//                          out[z*z_out + c*c_stride + r]
// gb3c points at gw3c+1024 (gate23_k reads them as one [1032] array).
// ---------------------------------------------------------------------------
__global__ void preproc_k(const void* x, bf16* xc,
                          const void* gb1, const void* gb2, const void* gw3,
                          const void* gb3, const void* eb1, const void* eb2,
                          const void* eb3,
                          bf16* gb1c, bf16* gb2c, bf16* gw3c, bf16* gb3c,
                          bf16* eb1c, bf16* eb2c, bf16* eb3c,
                          const void* gw1, const void* gw2,
                          const void* ew1, const void* ew2, const void* ew3,
                          bf16* gw1t, bf16* gw2t,
                          bf16* ew1t, bf16* ew2t, bf16* ew3t,
                          long ew3_zout, long ew3_cstride,
                          const int* __restrict__ flag) {
    const int f = *flag;
    const int tid = threadIdx.y * 32 + threadIdx.x;
    int lin = blockIdx.x;

    if (lin < 1024) {                 // ---- x convert ----
        const long n8 = (long)B_ * D_ / 8;
        long i = (long)lin * 256 + tid;
        const long stride = 1024 * 256;
        if (f) {
            const float4* s = (const float4*)x;
            for (; i < n8; i += stride) {
                float4 a = s[2 * i], b = s[2 * i + 1];
                bf16 tmp[8];
                tmp[0] = __float2bfloat16(a.x); tmp[1] = __float2bfloat16(a.y);
                tmp[2] = __float2bfloat16(a.z); tmp[3] = __float2bfloat16(a.w);
                tmp[4] = __float2bfloat16(b.x); tmp[5] = __float2bfloat16(b.y);
                tmp[6] = __float2bfloat16(b.z); tmp[7] = __float2bfloat16(b.w);
                *(uint4*)(xc + i * 8) = *(const uint4*)tmp;
            }
        } else {
            const uint4* s = (const uint4*)x;
            for (; i < n8; i += stride) *(uint4*)(xc + i * 8) = s[i];
        }
        return;
    }
    if (lin < 1031) {                 // ---- small converts ----
        const int id = lin - 1024;
        const void* sp[7] = {gb1, gb2, gw3, gb3, eb1, eb2, eb3};
        bf16* dp[7] = {gb1c, gb2c, gw3c, gb3c, eb1c, eb2c, eb3c};
        const int len[7] = {256, 128, 1024, 8, E_ * H_, E_ * H_, E_ * O_};
        const float* sf = (const float*)sp[id];
        const bf16*  sb = (const bf16*)sp[id];
        bf16* d = dp[id];
        for (int i = tid; i < len[id]; i += 256)
            d[i] = f ? __float2bfloat16(sf[i]) : sb[i];
        return;
    }
    lin -= 1031;                      // ---- transposes (round-6 verified) ----
    __shared__ bf16 t[32][33];
    const void* src; bf16* dst; int R, C, bx, by, bz; long z_out, c_stride;
    if (lin < 256) {
        src = gw1; dst = gw1t; R = 1024; C = 256; z_out = 0; c_stride = 1024;
        bx = lin & 7; by = lin >> 3; bz = 0;
    } else if (lin < 288) {
        lin -= 256;
        src = gw2; dst = gw2t; R = 256; C = 128; z_out = 0; c_stride = 256;
        bx = lin & 3; by = lin >> 2; bz = 0;
    } else if (lin < 4384) {
        lin -= 288;
        src = ew1; dst = ew1t; R = 1024; C = 512;
        z_out = (long)H_ * D_; c_stride = D_;
        bx = lin & 15; by = (lin >> 4) & 31; bz = lin >> 9;
    } else if (lin < 6432) {
        lin -= 4384;
        src = ew2; dst = ew2t; R = 512; C = 512;
        z_out = (long)H_ * H_; c_stride = H_;
        bx = lin & 15; by = (lin >> 4) & 15; bz = lin >> 8;
    } else {
        lin -= 6432;
        src = ew3; dst = ew3t; R = 512; C = 256;
        z_out = ew3_zout; c_stride = ew3_cstride;
        bx = lin & 7; by = (lin >> 3) & 15; bz = lin >> 7;
    }
    const long zi = (long)bz * R * C;
    const int xg = bx * 32 + threadIdx.x;
    const int y0 = by * 32;
    const float* inf = (const float*)src;
    const bf16* inb = (const bf16*)src;
#pragma unroll
    for (int i = 0; i < 4; i++) {
        int r = y0 + threadIdx.y + i * 8;
        long idx = zi + (long)r * C + xg;
        t[threadIdx.y + i * 8][threadIdx.x] =
            f ? __float2bfloat16(inf[idx]) : inb[idx];
    }
    __syncthreads();
    const int xr = by * 32 + threadIdx.x;
    const long zo = (long)bz * z_out;
#pragma unroll
    for (int i = 0; i < 4; i++) {
        int c = bx * 32 + threadIdx.y + i * 8;
        dst[zo + (long)c * c_stride + xr] = t[threadIdx.x][threadIdx.y + i * 8];
    }
}

// ---------------------------------------------------------------------------
// FUSED gating L2 + L3 + softmax (round-12/13/14 verified).
// ---------------------------------------------------------------------------
__global__ __launch_bounds__(256, 2)
void gate23_k(const bf16* __restrict__ A,      // g1 [B][256]
              const bf16* __restrict__ Bt,     // gw2t [128][256]
              const bf16* __restrict__ gb2,    // [128]
              const bf16* __restrict__ w3b,    // [1032]
              float* __restrict__ gates) {
    __shared__ __attribute__((aligned(16))) bf16 As[128 * 32];
    __shared__ __attribute__((aligned(16))) bf16 Bs[128 * 32];
    __shared__ bf16 t2[128][130];
    __shared__ float w3[1032];

    const int tid  = threadIdx.x;
    const int lane = tid & 63;
    const int quad = lane >> 4;
    const int l15  = lane & 15;
    const int wid  = tid >> 6;
    const int wr   = (wid >> 1) << 6;
    const int wc   = (wid & 1) << 6;
    const long m0  = (long)blockIdx.x << 7;

    for (int i = tid; i < 1032; i += 256) w3[i] = __bfloat162float(w3b[i]);

    f32x4 acc[4][4];
#pragma unroll
    for (int i = 0; i < 4; i++)
#pragma unroll
        for (int j = 0; j < 4; j++) acc[i][j] = (f32x4){0.f, 0.f, 0.f, 0.f};

    const int erow = tid >> 2;
    const int ecol = (tid & 3) << 3;

    for (int kti = 0; kti < 8; kti++) {        // K=256, BK=32
        const int kk = kti << 5;
#pragma unroll
        for (int i = 0; i < 2; i++) {
            const int r = (i << 6) + erow;
            GLDS(A + (m0 + r) * 256 + (kk + ecol), As + r * 32 + ecol);
        }
#pragma unroll
        for (int i = 0; i < 2; i++) {
            const int r = (i << 6) + erow;
            GLDS(Bt + (long)r * 256 + (kk + ecol), Bs + r * 32 + ecol);
        }
        __syncthreads();
        bf16x8 af[4], bfr[4];
#pragma unroll
        for (int i = 0; i < 4; i++)
            af[i] = *(const bf16x8*)(As + (wr + i * 16 + l15) * 32 + (quad << 3));
#pragma unroll
        for (int j = 0; j < 4; j++)
            bfr[j] = *(const bf16x8*)(Bs + (wc + j * 16 + l15) * 32 + (quad << 3));
#pragma unroll
        for (int i = 0; i < 4; i++)
#pragma unroll
            for (int j = 0; j < 4; j++)
                acc[i][j] = __builtin_amdgcn_mfma_f32_16x16x32_bf16(
                    af[i], bfr[j], acc[i][j], 0, 0, 0);
        __syncthreads();
    }

#pragma unroll
    for (int j = 0; j < 4; j++) {
        const int c = wc + j * 16 + l15;
        const float bv = __bfloat162float(gb2[c]);
#pragma unroll
        for (int i = 0; i < 4; i++)
#pragma unroll
            for (int rg = 0; rg < 4; rg++) {
                const int r = wr + i * 16 + quad * 4 + rg;
                t2[r][c] = __float2bfloat16(fmaxf(acc[i][j][rg] + bv, 0.f));
            }
    }
    __syncthreads();

    if (tid < 128) {
        const int r = tid;
        float a3[8];
#pragma unroll
        for (int o = 0; o < 8; o++) a3[o] = w3[1024 + o];
        for (int k = 0; k < 128; k++) {
            const float v = __bfloat162float(t2[r][k]);
#pragma unroll
            for (int o = 0; o < 8; o++) a3[o] += v * w3[k * 8 + o];
        }
        float mx = a3[0];
#pragma unroll
        for (int o = 1; o < 8; o++) mx = fmaxf(mx, a3[o]);
        float s = 0.f;
#pragma unroll
        for (int o = 0; o < 8; o++) { a3[o] = __expf(a3[o] - mx); s += a3[o]; }
        const float inv = 1.f / s;
#pragma unroll
        for (int o = 0; o < 8; o++) gates[(m0 + r) * 8 + o] = a3[o] * inv;
    }
}

// ---------------------------------------------------------------------------
// Legacy 128x128 GEMM (m97 structure, 4 blocks/CU). Round-14 finding: at
// shallow K (512) this beats the 8-phase 256-tile (hi=4 pipeline overhead +
// 1-block/CU); use it for expert L2. Also gating g1 + pathB fallback.
// MODE 0: out = bf16(relu(acc + bias[c]))
// MODE 1: out = bf16(relu(acc + bias[c]) * gates[row0+r, e])
// MODE 2: outf32[r,c] += acc + gates[row0+r,e]*eb3[e,c]
// ---------------------------------------------------------------------------
template <int MODE>
__global__ __launch_bounds__(256, 4)
void gemm_bt(const bf16* __restrict__ A, const bf16* __restrict__ Bt,
             const bf16* __restrict__ bias, const float* __restrict__ gates,
             void* __restrict__ Cout, const bf16* __restrict__ eb3,
             int lda, int ldb, int ldo, int K,
             long a_z, long b_z, long bias_z, long out_z,
             int e_gate, int k_per_e, long a_e, long b_e, long row0) {
    __shared__ __attribute__((aligned(16))) bf16 As[128 * 32];
    __shared__ __attribute__((aligned(16))) bf16 Bs[128 * 32];

    const int tid  = threadIdx.x;
    const int lane = tid & 63;
    const int quad = lane >> 4;
    const int l15  = lane & 15;
    const int wid  = tid >> 6;
    const int wr   = (wid >> 1) << 6;
    const int wc   = (wid & 1) << 6;
    const int z    = blockIdx.z;
    const long m0  = (long)blockIdx.y << 7;
    const long n0  = (long)blockIdx.x << 7;

    const bf16* Az = A + (long)z * a_z;
    const bf16* Bz = Bt + (long)z * b_z;

    f32x4 acc[4][4];
#pragma unroll
    for (int i = 0; i < 4; i++)
#pragma unroll
        for (int j = 0; j < 4; j++) acc[i][j] = (f32x4){0.f, 0.f, 0.f, 0.f};

    const int erow = tid >> 2;
    const int ecol = (tid & 3) << 3;

    const int n_e   = k_per_e ? (K / k_per_e) : 1;
    const int inner = (k_per_e ? k_per_e : K) >> 5;

    for (int e = 0; e < n_e; e++) {
        const bf16* Ae = Az + (long)e * a_e;
        const bf16* Be = Bz + (long)e * b_e;
        for (int kti = 0; kti < inner; kti++) {
            const int kk = kti << 5;
#pragma unroll
            for (int i = 0; i < 2; i++) {
                const int r = (i << 6) + erow;
                GLDS(Ae + (m0 + r) * lda + (kk + ecol), As + r * 32 + ecol);
            }
#pragma unroll
            for (int i = 0; i < 2; i++) {
                const int r = (i << 6) + erow;
                GLDS(Be + (n0 + r) * ldb + (kk + ecol), Bs + r * 32 + ecol);
            }
            __syncthreads();
            bf16x8 af[4], bfr[4];
#pragma unroll
            for (int i = 0; i < 4; i++)
                af[i] = *(const bf16x8*)(As + (wr + i * 16 + l15) * 32 + (quad << 3));
#pragma unroll
            for (int j = 0; j < 4; j++)
                bfr[j] = *(const bf16x8*)(Bs + (wc + j * 16 + l15) * 32 + (quad << 3));
#pragma unroll
            for (int i = 0; i < 4; i++)
#pragma unroll
                for (int j = 0; j < 4; j++)
                    acc[i][j] = __builtin_amdgcn_mfma_f32_16x16x32_bf16(
                        af[i], bfr[j], acc[i][j], 0, 0, 0);
            __syncthreads();
        }
    }

    const int eg = (e_gate >= 0) ? e_gate : z;

    if constexpr (MODE == 0 || MODE == 1) {
        bf16* C = (bf16*)Cout + (long)z * out_z;
        const bf16* bb = bias + (long)z * bias_z;
        float gv[4][4];
        if constexpr (MODE == 1) {
#pragma unroll
            for (int i = 0; i < 4; i++)
#pragma unroll
                for (int rg = 0; rg < 4; rg++)
                    gv[i][rg] = gates[(row0 + m0 + wr + i * 16 + quad * 4 + rg) * 8 + eg];
        }
#pragma unroll
        for (int j = 0; j < 4; j++) {
            const int c = (int)n0 + wc + j * 16 + l15;
            const float bv = __bfloat162float(bb[c]);
#pragma unroll
            for (int i = 0; i < 4; i++) {
#pragma unroll
                for (int rg = 0; rg < 4; rg++) {
                    const long r = m0 + wr + i * 16 + quad * 4 + rg;
                    float v = fmaxf(acc[i][j][rg] + bv, 0.f);
                    if constexpr (MODE == 1) v *= gv[i][rg];
                    C[r * ldo + c] = __float2bfloat16(v);
                }
            }
        }
    } else if constexpr (MODE == 2) {
        float* C = (float*)Cout;
#pragma unroll
        for (int i = 0; i < 4; i++) {
#pragma unroll
            for (int rg = 0; rg < 4; rg++) {
                const long r = m0 + wr + i * 16 + quad * 4 + rg;
                const float g = gates[(row0 + r) * 8 + eg];
#pragma unroll
                for (int j = 0; j < 4; j++) {
                    const int c = (int)n0 + wc + j * 16 + l15;
                    const float b3 = __bfloat162float(eb3[eg * O_ + c]);
                    C[r * ldo + c] += acc[i][j][rg] + g * b3;
                }
            }
        }
    }
}

// ---------------------------------------------------------------------------
// 256x256-tile 8-phase GEMM (m201 structure). ROUND-11/14 BYTE-IDENTICAL
// signature/source (MODE 0/1/4/5 all kept instantiated -- rule #19).
// Round-14 lesson: this kernel wins at K>=1024 (hi>=8); at K=512 (hi=4)
// prologue/drain dominate and gemm_bt (4 blocks/CU) is faster.
// MODE 0: bf16 out = relu(acc + bias[c])                    (z-batched)
// MODE 1: bf16 out = relu(acc + bias[c]) * gates[row0+r,z]  (z-batched)
// MODE 4: fp32 parts[z][r][c] = acc + gates[row0+r,z]*eb3[z,c]  (split-K z=8)
// MODE 5: fp32 parts[z] = acc + sum_{s<2} gates[row0+r,2z+s]*eb3[2z+s,c]
// ---------------------------------------------------------------------------
template <int MODE>
__global__ __launch_bounds__(512, 2)
void gemm256(const bf16* __restrict__ A, const bf16* __restrict__ Bt,
             const bf16* __restrict__ bias, const float* __restrict__ gates,
             void* __restrict__ Cout, const bf16* __restrict__ eb3,
             int lda, int ldb, int ldo, int K,
             long a_z, long b_z, long bias_z, long out_z, long row0) {
    __shared__ __attribute__((aligned(16))) bf16 lds[2][2][256 * 64];

    // T1: bijective XCD swizzle (nwg per z-slice is a multiple of 8 everywhere)
    int bx = blockIdx.x, by = blockIdx.y;
    {
        const int gx = gridDim.x;
        const int nwg = gx * gridDim.y;
        if ((nwg & 7) == 0) {
            int lin = bx + gx * by;
            lin = (lin & 7) * (nwg >> 3) + (lin >> 3);
            bx = lin % gx; by = lin / gx;
        }
    }

    const int tid  = threadIdx.x;
    const int lane = tid & 63;
    const int quad = lane >> 4;
    const int l15  = lane & 15;
    const int w    = tid >> 6;
    const int wm   = w >> 2;
    const int wn   = w & 3;
    const int z    = blockIdx.z;
    const long m0  = (long)by << 8;
    const long n0  = (long)bx << 8;

    const bf16* __restrict__ Az = A + z * a_z;
    const bf16* __restrict__ Bz = Bt + z * b_z;

    f32x4 acc[8][4];
#pragma unroll
    for (int i = 0; i < 8; ++i)
#pragma unroll
        for (int j = 0; j < 4; ++j) acc[i][j] = (f32x4){0.f, 0.f, 0.f, 0.f};

    bf16x8 af[4][2], bv[2][2];

    auto stage = [&](int buf, int mat, int half, int kt) {
        const bf16* __restrict__ G = mat ? Bz : Az;
        const int ld = mat ? ldb : lda;
        const long p0 = mat ? n0 : m0;
#pragma unroll
        for (int l = 0; l < 2; ++l) {
            const int ci = (w << 1) | l;                       // 0..15, wave-uniform
            const int rb = mat ? ((ci >> 2) << 6) + (half << 5) + ((ci & 3) << 3)
                               : ((ci >> 3) << 7) + (half << 6) + ((ci & 7) << 3);
            const int row = rb + (lane >> 3);
            const int cb  = ((lane & 7) << 4) ^ ((row & 7) << 4);  // T2 inverse-swz src
            GLDS(G + (p0 + row) * ld + kt * 64 + (cb >> 1),
                 &lds[buf][mat][rb * 64]);
        }
    };
    auto ldaf = [&](int buf, int qm) {
#pragma unroll
        for (int i = 0; i < 4; ++i) {
            const int r = (wm << 7) + (qm << 6) + (i << 4) + l15;
            const char* p = (const char*)&lds[buf][0][r * 64];
            const int sw = (r & 7) << 4;
#pragma unroll
            for (int s = 0; s < 2; ++s)
                af[i][s] = *(const bf16x8*)(p + (((s << 6) + (quad << 4)) ^ sw));
        }
    };
    auto ldbf = [&](int buf, int qn) {
#pragma unroll
        for (int j = 0; j < 2; ++j) {
            const int r = (wn << 6) + (qn << 5) + (j << 4) + l15;
            const char* p = (const char*)&lds[buf][1][r * 64];
            const int sw = (r & 7) << 4;
#pragma unroll
            for (int s = 0; s < 2; ++s)
                bv[j][s] = *(const bf16x8*)(p + (((s << 6) + (quad << 4)) ^ sw));
        }
    };
    auto mmac = [&](int qm, int qn) {
#pragma unroll
        for (int i = 0; i < 4; ++i)
#pragma unroll
            for (int j = 0; j < 2; ++j)
#pragma unroll
                for (int s = 0; s < 2; ++s)
                    acc[(qm << 2) + i][(qn << 1) + j] =
                        __builtin_amdgcn_mfma_f32_16x16x32_bf16(
                            af[i][s], bv[j][s], acc[(qm << 2) + i][(qn << 1) + j],
                            0, 0, 0);
    };

    const int nt = K >> 6;           // K-tiles (even, >=2 at all call sites)

    // prologue: tile0 full -> buf0; tile1 halves0 -> buf1; guarantee tile0.
    stage(0, 0, 0, 0); stage(0, 0, 1, 0); stage(0, 1, 0, 0); stage(0, 1, 1, 0);
    stage(1, 0, 0, 1); stage(1, 1, 0, 1);
    asm volatile("s_waitcnt vmcnt(4)" ::: "memory");
    BAR();

    const int hi = nt >> 1;
    for (int it = 0; it < hi; ++it) {
        const int t1k = 2 * it + 1, t2k = 2 * it + 2, t3k = 2 * it + 3;
        const bool do2 = t2k < nt, do3 = t3k < nt;
        // P0
        ldaf(0, 0); ldbf(0, 0); stage(1, 0, 1, t1k);
        BAR(); LGKM0();
        __builtin_amdgcn_s_setprio(1); mmac(0, 0); __builtin_amdgcn_s_setprio(0);
        BAR();
        // P1
        ldbf(0, 1); stage(1, 1, 1, t1k);
        BAR(); LGKM0();
        __builtin_amdgcn_s_setprio(1); mmac(0, 1); __builtin_amdgcn_s_setprio(0);
        BAR();
        // P2
        ldaf(0, 1); ldbf(0, 0); if (do2) stage(0, 0, 0, t2k);
        BAR(); LGKM0();
        __builtin_amdgcn_s_setprio(1); mmac(1, 0); __builtin_amdgcn_s_setprio(0);
        BAR();
        // P3
        ldbf(0, 1); if (do2) stage(0, 1, 0, t2k);
        BAR(); LGKM0();
        __builtin_amdgcn_s_setprio(1); mmac(1, 1); __builtin_amdgcn_s_setprio(0);
        if (do2) { asm volatile("s_waitcnt vmcnt(4)" ::: "memory"); }
        else     { asm volatile("s_waitcnt vmcnt(0)" ::: "memory"); }
        BAR();
        // P4
        ldaf(1, 0); ldbf(1, 0); if (do2) stage(0, 0, 1, t2k);
        BAR(); LGKM0();
        __builtin_amdgcn_s_setprio(1); mmac(0, 0); __builtin_amdgcn_s_setprio(0);
        BAR();
        // P5
        ldbf(1, 1); if (do2) stage(0, 1, 1, t2k);
        BAR(); LGKM0();
        __builtin_amdgcn_s_setprio(1); mmac(0, 1); __builtin_amdgcn_s_setprio(0);
        BAR();
        // P6
        ldaf(1, 1); ldbf(1, 0); if (do3) stage(1, 0, 0, t3k);
        BAR(); LGKM0();
        __builtin_amdgcn_s_setprio(1); mmac(1, 0); __builtin_amdgcn_s_setprio(0);
        BAR();
        // P7
        ldbf(1, 1); if (do3) stage(1, 1, 0, t3k);
        BAR(); LGKM0();
        __builtin_amdgcn_s_setprio(1); mmac(1, 1); __builtin_amdgcn_s_setprio(0);
        if (do3) { asm volatile("s_waitcnt vmcnt(4)" ::: "memory"); }
        else     { asm volatile("s_waitcnt vmcnt(0)" ::: "memory"); }
        BAR();
    }

    // ---------------- epilogue (C/D: row=quad*4+reg, col=l15) --------------
    if constexpr (MODE == 0 || MODE == 1) {
        bf16* C = (bf16*)Cout + z * out_z;
        const bf16* bb = bias + z * bias_z;
        float bvv[4];
#pragma unroll
        for (int jg = 0; jg < 4; ++jg)
            bvv[jg] = __bfloat162float(bb[(int)n0 + (wn << 6) + (jg << 4) + l15]);
#pragma unroll
        for (int ig = 0; ig < 8; ++ig) {
#pragma unroll
            for (int rg = 0; rg < 4; ++rg) {
                const long r = m0 + (wm << 7) + (ig << 4) + (quad << 2) + rg;
                float g = 1.f;
                if constexpr (MODE == 1) g = gates[(row0 + r) * 8 + z];
#pragma unroll
                for (int jg = 0; jg < 4; ++jg) {
                    const int c = (int)n0 + (wn << 6) + (jg << 4) + l15;
                    float v = fmaxf(acc[ig][jg][rg] + bvv[jg], 0.f);
                    if constexpr (MODE == 1) v *= g;
                    C[r * ldo + c] = __float2bfloat16(v);
                }
            }
        }
    } else if constexpr (MODE == 4) {  // split-K z=8 partials, plain stores
        float* C = (float*)Cout + z * out_z;
        float b3v[4];
#pragma unroll
        for (int jg = 0; jg < 4; ++jg)
            b3v[jg] = __bfloat162float(eb3[z * O_ + (int)n0 + (wn << 6) + (jg << 4) + l15]);
#pragma unroll
        for (int ig = 0; ig < 8; ++ig) {
#pragma unroll
            for (int rg = 0; rg < 4; ++rg) {
                const long r = m0 + (wm << 7) + (ig << 4) + (quad << 2) + rg;
                const float g = gates[(row0 + r) * 8 + z];
#pragma unroll
                for (int jg = 0; jg < 4; ++jg) {
                    const int c = (int)n0 + (wn << 6) + (jg << 4) + l15;
                    C[r * ldo + c] = acc[ig][jg][rg] + g * b3v[jg];
                }
            }
        }
    } else {  // MODE 5: pair split-K partials (experts 2z, 2z+1)
        float* C = (float*)Cout + z * out_z;
        const int e0 = z << 1;
        float b30[4], b31[4];
#pragma unroll
        for (int jg = 0; jg < 4; ++jg) {
            const int c = (int)n0 + (wn << 6) + (jg << 4) + l15;
            b30[jg] = __bfloat162float(eb3[e0 * O_ + c]);
            b31[jg] = __bfloat162float(eb3[(e0 + 1) * O_ + c]);
        }
#pragma unroll
        for (int ig = 0; ig < 8; ++ig) {
#pragma unroll
            for (int rg = 0; rg < 4; ++rg) {
                const long r = m0 + (wm << 7) + (ig << 4) + (quad << 2) + rg;
                const float g0 = gates[(row0 + r) * 8 + e0];
                const float g1 = gates[(row0 + r) * 8 + e0 + 1];
#pragma unroll
                for (int jg = 0; jg < 4; ++jg) {
                    const int c = (int)n0 + (wn << 6) + (jg << 4) + l15;
                    C[r * ldo + c] = acc[ig][jg][rg] + g0 * b30[jg] + g1 * b31[jg];
                }
            }
        }
    }
}

// ---------------------------------------------------------------------------
__global__ void zero_f32_k(float* __restrict__ p) {
    p[(long)blockIdx.x * 256 + threadIdx.x] = 0.f;
}
__global__ void out_cvt_k(const float* __restrict__ in, void* __restrict__ out,
                          const int* __restrict__ flag) {
    const long i = (long)blockIdx.x * 256 + threadIdx.x;
    if (*flag) ((float*)out)[i] = in[i];
    else       ((bf16*)out)[i] = __float2bfloat16(in[i]);
}
// sum NZ split-K partial buffers [NZ][n] -> out rows [off..off+n)
template <int NZ>
__global__ void reduceN_k(const float* __restrict__ p, void* __restrict__ out,
                          const int* __restrict__ flag, long n, long off) {
    const long i = ((long)blockIdx.x * 256 + threadIdx.x) * 4;
    float4 s = *(const float4*)(p + i);
#pragma unroll
    for (int zz = 1; zz < NZ; ++zz) {
        float4 a = *(const float4*)(p + (long)zz * n + i);
        s.x += a.x; s.y += a.y; s.z += a.z; s.w += a.w;
    }
    if (*flag) {
        *(float4*)((float*)out + off + i) = s;
    } else {
        bf16* o = (bf16*)out + off + i;
        o[0] = __float2bfloat16(s.x); o[1] = __float2bfloat16(s.y);
        o[2] = __float2bfloat16(s.z); o[3] = __float2bfloat16(s.w);
    }
}

// ---------------------------------------------------------------------------
extern "C" void kernel_launch(void* const* d_in, const int* in_sizes, int n_in,
                              void* d_out, int out_size, void* d_ws, size_t ws_size,
                              hipStream_t stream) {
    (void)in_sizes; (void)n_in; (void)out_size;
    const void* x   = d_in[0];
    const void* gw1 = d_in[1];
    const void* gb1 = d_in[2];
    const void* gw2 = d_in[3];
    const void* gb2 = d_in[4];
    const void* gw3 = d_in[5];
    const void* gb3 = d_in[6];
    const void* ew1 = d_in[7];
    const void* eb1 = d_in[8];
    const void* ew2 = d_in[9];
    const void* eb2 = d_in[10];
    const void* ew3 = d_in[11];
    const void* eb3 = d_in[12];

    char* ws = (char*)d_ws;
    size_t off = 0;
    auto alloc = [&](size_t n) { char* p = ws + off; off += (n + 255) & ~(size_t)255; return p; };

    int*  flag  = (int*)alloc(256);
    bf16* xc    = (bf16*)alloc((size_t)B_ * D_ * 2);
    bf16* ew1t  = (bf16*)alloc((size_t)E_ * H_ * D_ * 2);
    bf16* gw1t  = (bf16*)alloc((size_t)256 * 1024 * 2);
    bf16* gw2t  = (bf16*)alloc((size_t)128 * 256 * 2);
    bf16* ew2t  = (bf16*)alloc((size_t)E_ * H_ * H_ * 2);
    bf16* ew3t  = (bf16*)alloc((size_t)E_ * O_ * H_ * 2);
    bf16* eb1c  = (bf16*)alloc((size_t)E_ * H_ * 2);
    bf16* gb1c  = (bf16*)alloc(256 * 2);
    bf16* gb2c  = (bf16*)alloc(128 * 2);
    bf16* gw3c  = (bf16*)alloc(1032 * 2);        // [0..1023]=gw3, [1024..1031]=gb3
    bf16* gb3c  = gw3c + 1024;
    bf16* eb2c  = (bf16*)alloc((size_t)E_ * H_ * 2);
    bf16* eb3c  = (bf16*)alloc((size_t)E_ * O_ * 2);
    float* gates = (float*)alloc((size_t)B_ * 8 * 4);
    bf16* g1    = (bf16*)alloc((size_t)B_ * 256 * 2);

    const size_t smallCore = off;
    // pathPair : h1c [E][BC][H] (64 MiB, reused per chunk) + h2 FULL [B][4096]
    //            (128 MiB); parts4 (64 MiB) ALIASES h1c. (round-11/14 verified)
    // pathChunk: h1c + h2c [BC][4096] + parts8 (round-9 verified fallback).
    const size_t needPair = smallCore + ((size_t)E_ * BC_ * H_ * 2 + 256)
                                      + ((size_t)B_ * E_ * H_ * 2 + 256) + 4096;
    const size_t needChunk = smallCore + ((size_t)E_ * BC_ * H_ * 2 + 256)
                                       + ((size_t)BC_ * E_ * H_ * 2 + 256)
                                       + (8ull * BC_ * O_ * 4 + 256) + 4096;
    const bool pathPair  = ws_size >= needPair;
    const bool pathChunk = ws_size >= needChunk;

    // 1) DEVICE-side dtype detect (element counts are dtype-blind on host)
    detect_k<<<1, 256, 0, stream>>>((const unsigned short*)x, flag);

    // 2) all preprocessing in one launch (ew3t layout per path)
    const bool l3pair = pathPair || pathChunk;
    const long e3zo = l3pair ? (long)H_ : (long)O_ * H_;   // [O][E*H] vs [E][O][H]
    const long e3cs = l3pair ? (long)E_ * H_ : (long)H_;
    preproc_k<<<8487, dim3(32, 8), 0, stream>>>(
        x, xc, gb1, gb2, gw3, gb3, eb1, eb2, eb3,
        gb1c, gb2c, gw3c, gb3c, eb1c, eb2c, eb3c,
        gw1, gw2, ew1, ew2, ew3, gw1t, gw2t, ew1t, ew2t, ew3t,
        e3zo, e3cs, flag);

    // 3) gating: g1 GEMM, then FUSED g2+g3+softmax (one launch)
    gemm_bt<0><<<dim3(2, 128, 1), 256, 0, stream>>>(
        xc, gw1t, gb1c, nullptr, g1, nullptr,
        1024, 1024, 256, 1024, 0, 0, 0, 0, 0, 0, 0, 0, 0);
    gate23_k<<<dim3(128), 256, 0, stream>>>(g1, gw2t, gb2c, gw3c, gates);

    // 4) experts
    if (pathPair) {
        bf16* h1c = (bf16*)alloc((size_t)E_ * BC_ * H_ * 2);     // [E][BC][H]
        bf16* h2  = (bf16*)alloc((size_t)B_ * E_ * H_ * 2);      // [B][4096] full
        float* parts = (float*)h1c;                              // alias (64 MiB)

        for (int ch = 0; ch < B_ / BC_; ch++) {
            const long rb = (long)ch * BC_;
            // L1 chunk: gemm256 (K=1024, hi=8 -- its winning regime)
            gemm256<0><<<dim3(2, BC_ / 256, 8), 512, 0, stream>>>(
                xc + rb * D_, ew1t, eb1c, nullptr, h1c, nullptr,
                D_, D_, H_, D_,
                0, (long)H_ * D_, (long)H_, (long)BC_ * H_, 0);
            // L2 chunk: gemm_bt (K=512 -- shallow-K regime; 2048 blocks =
            // 4 blocks/CU wave-overlap; round-14 finding). Writes FULL h2
            // [B][E*H]: Cout offset rb*E*H, per-z column offset out_z=H.
            gemm_bt<1><<<dim3(4, BC_ / 128, 8), 256, 0, stream>>>(
                h1c, ew2t, eb2c, gates, h2 + rb * (long)E_ * H_, nullptr,
                H_, H_, E_ * H_, H_,
                (long)BC_ * H_, (long)H_ * H_, (long)H_, (long)H_,
                -1, 0, 0, 0, rb);
        }
        // L3 pair split-K over full B: z=4, K=1024, grid (1,64,4) = 256
        // blocks = 1 round; separate full-grid reduce (round-13 lesson).
        gemm256<5><<<dim3(1, B_ / 256, 4), 512, 0, stream>>>(
            h2, ew3t, nullptr, gates, parts, eb3c,
            E_ * H_, E_ * H_, O_, 1024,
            2L * H_, 2L * H_, 0, (long)B_ * O_, 0);
        reduceN_k<4><<<dim3(B_ * O_ / 1024), 256, 0, stream>>>(
            parts, d_out, flag, (long)B_ * O_, 0L);
    } else if (pathChunk) {
        bf16* h1c = (bf16*)alloc((size_t)E_ * BC_ * H_ * 2);     // [E][BC][H]
        bf16* h2c = (bf16*)alloc((size_t)BC_ * E_ * H_ * 2);     // [BC][E*H]
        float* parts = (float*)alloc(8ull * BC_ * O_ * 4);       // [8][BC][O]

        for (int ch = 0; ch < B_ / BC_; ch++) {
            const long rb = (long)ch * BC_;
            gemm256<0><<<dim3(2, BC_ / 256, 8), 512, 0, stream>>>(
                xc + rb * D_, ew1t, eb1c, nullptr, h1c, nullptr,
                D_, D_, H_, D_,
                0, (long)H_ * D_, (long)H_, (long)BC_ * H_, 0);
            gemm256<1><<<dim3(2, BC_ / 256, 8), 512, 0, stream>>>(
                h1c, ew2t, eb2c, gates, h2c, nullptr,
                H_, H_, E_ * H_, H_,
                (long)BC_ * H_, (long)H_ * H_, (long)H_, (long)H_, rb);
            gemm256<4><<<dim3(1, BC_ / 256, 8), 512, 0, stream>>>(
                h2c, ew3t, nullptr, gates, parts, eb3c,
                E_ * H_, E_ * H_, O_, 512,
                (long)H_, (long)H_, 0, (long)BC_ * O_, rb);
            reduceN_k<8><<<dim3(BC_ * O_ / 1024), 256, 0, stream>>>(
                parts, d_out, flag, (long)BC_ * O_, rb * O_);
        }
    } else {
        bf16* h1s = (bf16*)alloc((size_t)B_ * H_ * 2);
        bf16* h2s = (bf16*)alloc((size_t)B_ * H_ * 2);
        float* oacc = (float*)alloc((size_t)B_ * O_ * 4);
        zero_f32_k<<<dim3(B_ * O_ / 256), 256, 0, stream>>>(oacc);
        for (int e = 0; e < E_; e++) {
            gemm_bt<0><<<dim3(4, 128, 1), 256, 0, stream>>>(
                xc, ew1t + (size_t)e * H_ * D_, eb1c + (size_t)e * H_, nullptr, h1s, nullptr,
                1024, 1024, 512, 1024, 0, 0, 0, 0, 0, 0, 0, 0, 0);
            gemm_bt<1><<<dim3(4, 128, 1), 256, 0, stream>>>(
                h1s, ew2t + (size_t)e * H_ * H_, eb2c + (size_t)e * H_, gates, h2s, nullptr,
                512, 512, 512, 512, 0, 0, 0, 0, e, 0, 0, 0, 0);
            gemm_bt<2><<<dim3(2, 128, 1), 256, 0, stream>>>(
                h2s, ew3t + (size_t)e * O_ * H_, nullptr, gates, oacc, eb3c,
                512, 512, 256, 512, 0, 0, 0, 0, e, 0, 0, 0, 0);
        }
        out_cvt_k<<<dim3(B_ * O_ / 256), 256, 0, stream>>>(oacc, d_out, flag);
    }
}

// Round 16
// 485.698 us; speedup vs baseline: 1.0804x; 1.0804x over previous
//
#include <hip/hip_runtime.h>
#include <hip/hip_bf16.h>

typedef __hip_bfloat16 bf16;
typedef __attribute__((ext_vector_type(8))) __bf16 bf16x8;
typedef __attribute__((ext_vector_type(4))) float f32x4;

#define B_ 16384
#define D_ 1024
#define H_ 512
#define O_ 256
#define E_ 8
#define BC_ 8192   // B-chunk rows

static_assert(B_ % BC_ == 0, "chunking");

// async global->LDS, 16B per lane (m97/m201 staging path).
#define GLDS(src, dst) __builtin_amdgcn_global_load_lds( \
    (const __attribute__((address_space(1))) void*)(src), \
    (__attribute__((address_space(3))) void*)(dst), 16, 0, 0)

#define BAR()   asm volatile("s_barrier" ::: "memory")
#define LGKM0() do { asm volatile("s_waitcnt lgkmcnt(0)" ::: "memory"); \
                     __builtin_amdgcn_sched_barrier(0); } while (0)

// ---------------------------------------------------------------------------
// Input-dtype detector (DEVICE-side; in_sizes are ELEMENT counts, dtype-blind
// on host -- round-5 lesson). flag=1 => inputs are fp32. ROUND-11 FORM.
// ---------------------------------------------------------------------------
__global__ void detect_k(const unsigned short* __restrict__ x, int* __restrict__ flag) {
    __shared__ int s;
    if (threadIdx.x == 0) s = 0;
    __syncthreads();
    int big = 0;
    for (int i = threadIdx.x; i < 2048; i += 256)
        if (((x[i] >> 7) & 0xFF) >= 150) big = 1;
    if (big) atomicOr(&s, 1);
    __syncthreads();
    if (threadIdx.x == 0) *flag = s;
}

// ---------------------------------------------------------------------------
// ALL preprocessing in ONE launch (round-8..14 verified).
//   blocks [0,1024)      : x canonicalize (vectorized)
//   blocks [1024,1031)   : 7 small bias/weight converts
//   blocks [1031,8487)   : 5 weight transposes, in [Z][R][C] ->
//                          out[z*z_out + c*c_stride + r]
// gb3c points at gw3c+1024 (gate23_k reads them as one [1032] array).
// ---------------------------------------------------------------------------
__global__ void preproc_k(const void* x, bf16* xc,
                          const void* gb1, const void* gb2, const void* gw3,
                          const void* gb3, const void* eb1, const void* eb2,
                          const void* eb3,
                          bf16* gb1c, bf16* gb2c, bf16* gw3c, bf16* gb3c,
                          bf16* eb1c, bf16* eb2c, bf16* eb3c,
                          const void* gw1, const void* gw2,
                          const void* ew1, const void* ew2, const void* ew3,
                          bf16* gw1t, bf16* gw2t,
                          bf16* ew1t, bf16* ew2t, bf16* ew3t,
                          long ew3_zout, long ew3_cstride,
                          const int* __restrict__ flag) {
    const int f = *flag;
    const int tid = threadIdx.y * 32 + threadIdx.x;
    int lin = blockIdx.x;

    if (lin < 1024) {                 // ---- x convert ----
        const long n8 = (long)B_ * D_ / 8;
        long i = (long)lin * 256 + tid;
        const long stride = 1024 * 256;
        if (f) {
            const float4* s = (const float4*)x;
            for (; i < n8; i += stride) {
                float4 a = s[2 * i], b = s[2 * i + 1];
                bf16 tmp[8];
                tmp[0] = __float2bfloat16(a.x); tmp[1] = __float2bfloat16(a.y);
                tmp[2] = __float2bfloat16(a.z); tmp[3] = __float2bfloat16(a.w);
                tmp[4] = __float2bfloat16(b.x); tmp[5] = __float2bfloat16(b.y);
                tmp[6] = __float2bfloat16(b.z); tmp[7] = __float2bfloat16(b.w);
                *(uint4*)(xc + i * 8) = *(const uint4*)tmp;
            }
        } else {
            const uint4* s = (const uint4*)x;
            for (; i < n8; i += stride) *(uint4*)(xc + i * 8) = s[i];
        }
        return;
    }
    if (lin < 1031) {                 // ---- small converts ----
        const int id = lin - 1024;
        const void* sp[7] = {gb1, gb2, gw3, gb3, eb1, eb2, eb3};
        bf16* dp[7] = {gb1c, gb2c, gw3c, gb3c, eb1c, eb2c, eb3c};
        const int len[7] = {256, 128, 1024, 8, E_ * H_, E_ * H_, E_ * O_};
        const float* sf = (const float*)sp[id];
        const bf16*  sb = (const bf16*)sp[id];
        bf16* d = dp[id];
        for (int i = tid; i < len[id]; i += 256)
            d[i] = f ? __float2bfloat16(sf[i]) : sb[i];
        return;
    }
    lin -= 1031;                      // ---- transposes (round-6 verified) ----
    __shared__ bf16 t[32][33];
    const void* src; bf16* dst; int R, C, bx, by, bz; long z_out, c_stride;
    if (lin < 256) {
        src = gw1; dst = gw1t; R = 1024; C = 256; z_out = 0; c_stride = 1024;
        bx = lin & 7; by = lin >> 3; bz = 0;
    } else if (lin < 288) {
        lin -= 256;
        src = gw2; dst = gw2t; R = 256; C = 128; z_out = 0; c_stride = 256;
        bx = lin & 3; by = lin >> 2; bz = 0;
    } else if (lin < 4384) {
        lin -= 288;
        src = ew1; dst = ew1t; R = 1024; C = 512;
        z_out = (long)H_ * D_; c_stride = D_;
        bx = lin & 15; by = (lin >> 4) & 31; bz = lin >> 9;
    } else if (lin < 6432) {
        lin -= 4384;
        src = ew2; dst = ew2t; R = 512; C = 512;
        z_out = (long)H_ * H_; c_stride = H_;
        bx = lin & 15; by = (lin >> 4) & 15; bz = lin >> 8;
    } else {
        lin -= 6432;
        src = ew3; dst = ew3t; R = 512; C = 256;
        z_out = ew3_zout; c_stride = ew3_cstride;
        bx = lin & 7; by = (lin >> 3) & 15; bz = lin >> 7;
    }
    const long zi = (long)bz * R * C;
    const int xg = bx * 32 + threadIdx.x;
    const int y0 = by * 32;
    const float* inf = (const float*)src;
    const bf16* inb = (const bf16*)src;
#pragma unroll
    for (int i = 0; i < 4; i++) {
        int r = y0 + threadIdx.y + i * 8;
        long idx = zi + (long)r * C + xg;
        t[threadIdx.y + i * 8][threadIdx.x] =
            f ? __float2bfloat16(inf[idx]) : inb[idx];
    }
    __syncthreads();
    const int xr = by * 32 + threadIdx.x;
    const long zo = (long)bz * z_out;
#pragma unroll
    for (int i = 0; i < 4; i++) {
        int c = bx * 32 + threadIdx.y + i * 8;
        dst[zo + (long)c * c_stride + xr] = t[threadIdx.x][threadIdx.y + i * 8];
    }
}

// ---------------------------------------------------------------------------
// FUSED gating L2 + L3 + softmax (round-12/13/14 verified). One block = 128
// rows x all 128 g2 cols (m97 K-loop, K=256); g3 + row-softmax in-epilogue.
// ---------------------------------------------------------------------------
__global__ __launch_bounds__(256, 2)
void gate23_k(const bf16* __restrict__ A,      // g1 [B][256]
              const bf16* __restrict__ Bt,     // gw2t [128][256]
              const bf16* __restrict__ gb2,    // [128]
              const bf16* __restrict__ w3b,    // [1032]
              float* __restrict__ gates) {
    __shared__ __attribute__((aligned(16))) bf16 As[128 * 32];
    __shared__ __attribute__((aligned(16))) bf16 Bs[128 * 32];
    __shared__ bf16 t2[128][130];
    __shared__ float w3[1032];

    const int tid  = threadIdx.x;
    const int lane = tid & 63;
    const int quad = lane >> 4;
    const int l15  = lane & 15;
    const int wid  = tid >> 6;
    const int wr   = (wid >> 1) << 6;
    const int wc   = (wid & 1) << 6;
    const long m0  = (long)blockIdx.x << 7;

    for (int i = tid; i < 1032; i += 256) w3[i] = __bfloat162float(w3b[i]);

    f32x4 acc[4][4];
#pragma unroll
    for (int i = 0; i < 4; i++)
#pragma unroll
        for (int j = 0; j < 4; j++) acc[i][j] = (f32x4){0.f, 0.f, 0.f, 0.f};

    const int erow = tid >> 2;
    const int ecol = (tid & 3) << 3;

    for (int kti = 0; kti < 8; kti++) {        // K=256, BK=32
        const int kk = kti << 5;
#pragma unroll
        for (int i = 0; i < 2; i++) {
            const int r = (i << 6) + erow;
            GLDS(A + (m0 + r) * 256 + (kk + ecol), As + r * 32 + ecol);
        }
#pragma unroll
        for (int i = 0; i < 2; i++) {
            const int r = (i << 6) + erow;
            GLDS(Bt + (long)r * 256 + (kk + ecol), Bs + r * 32 + ecol);
        }
        __syncthreads();
        bf16x8 af[4], bfr[4];
#pragma unroll
        for (int i = 0; i < 4; i++)
            af[i] = *(const bf16x8*)(As + (wr + i * 16 + l15) * 32 + (quad << 3));
#pragma unroll
        for (int j = 0; j < 4; j++)
            bfr[j] = *(const bf16x8*)(Bs + (wc + j * 16 + l15) * 32 + (quad << 3));
#pragma unroll
        for (int i = 0; i < 4; i++)
#pragma unroll
            for (int j = 0; j < 4; j++)
                acc[i][j] = __builtin_amdgcn_mfma_f32_16x16x32_bf16(
                    af[i], bfr[j], acc[i][j], 0, 0, 0);
        __syncthreads();
    }

#pragma unroll
    for (int j = 0; j < 4; j++) {
        const int c = wc + j * 16 + l15;
        const float bv = __bfloat162float(gb2[c]);
#pragma unroll
        for (int i = 0; i < 4; i++)
#pragma unroll
            for (int rg = 0; rg < 4; rg++) {
                const int r = wr + i * 16 + quad * 4 + rg;
                t2[r][c] = __float2bfloat16(fmaxf(acc[i][j][rg] + bv, 0.f));
            }
    }
    __syncthreads();

    if (tid < 128) {
        const int r = tid;
        float a3[8];
#pragma unroll
        for (int o = 0; o < 8; o++) a3[o] = w3[1024 + o];
        for (int k = 0; k < 128; k++) {
            const float v = __bfloat162float(t2[r][k]);
#pragma unroll
            for (int o = 0; o < 8; o++) a3[o] += v * w3[k * 8 + o];
        }
        float mx = a3[0];
#pragma unroll
        for (int o = 1; o < 8; o++) mx = fmaxf(mx, a3[o]);
        float s = 0.f;
#pragma unroll
        for (int o = 0; o < 8; o++) { a3[o] = __expf(a3[o] - mx); s += a3[o]; }
        const float inv = 1.f / s;
#pragma unroll
        for (int o = 0; o < 8; o++) gates[(m0 + r) * 8 + o] = a3[o] * inv;
    }
}

// ---------------------------------------------------------------------------
// Legacy 128x128 GEMM (m97 structure). Round-7 lesson: grid-starved below
// ~3*256 blocks. Used only for gating g1 + pathB fallback.
// ---------------------------------------------------------------------------
template <int MODE>
__global__ __launch_bounds__(256, 4)
void gemm_bt(const bf16* __restrict__ A, const bf16* __restrict__ Bt,
             const bf16* __restrict__ bias, const float* __restrict__ gates,
             void* __restrict__ Cout, const bf16* __restrict__ eb3,
             int lda, int ldb, int ldo, int K,
             long a_z, long b_z, long bias_z, long out_z,
             int e_gate, int k_per_e, long a_e, long b_e, long row0) {
    __shared__ __attribute__((aligned(16))) bf16 As[128 * 32];
    __shared__ __attribute__((aligned(16))) bf16 Bs[128 * 32];

    const int tid  = threadIdx.x;
    const int lane = tid & 63;
    const int quad = lane >> 4;
    const int l15  = lane & 15;
    const int wid  = tid >> 6;
    const int wr   = (wid >> 1) << 6;
    const int wc   = (wid & 1) << 6;
    const int z    = blockIdx.z;
    const long m0  = (long)blockIdx.y << 7;
    const long n0  = (long)blockIdx.x << 7;

    const bf16* Az = A + (long)z * a_z;
    const bf16* Bz = Bt + (long)z * b_z;

    f32x4 acc[4][4];
#pragma unroll
    for (int i = 0; i < 4; i++)
#pragma unroll
        for (int j = 0; j < 4; j++) acc[i][j] = (f32x4){0.f, 0.f, 0.f, 0.f};

    const int erow = tid >> 2;
    const int ecol = (tid & 3) << 3;

    const int n_e   = k_per_e ? (K / k_per_e) : 1;
    const int inner = (k_per_e ? k_per_e : K) >> 5;

    for (int e = 0; e < n_e; e++) {
        const bf16* Ae = Az + (long)e * a_e;
        const bf16* Be = Bz + (long)e * b_e;
        for (int kti = 0; kti < inner; kti++) {
            const int kk = kti << 5;
#pragma unroll
            for (int i = 0; i < 2; i++) {
                const int r = (i << 6) + erow;
                GLDS(Ae + (m0 + r) * lda + (kk + ecol), As + r * 32 + ecol);
            }
#pragma unroll
            for (int i = 0; i < 2; i++) {
                const int r = (i << 6) + erow;
                GLDS(Be + (n0 + r) * ldb + (kk + ecol), Bs + r * 32 + ecol);
            }
            __syncthreads();
            bf16x8 af[4], bfr[4];
#pragma unroll
            for (int i = 0; i < 4; i++)
                af[i] = *(const bf16x8*)(As + (wr + i * 16 + l15) * 32 + (quad << 3));
#pragma unroll
            for (int j = 0; j < 4; j++)
                bfr[j] = *(const bf16x8*)(Bs + (wc + j * 16 + l15) * 32 + (quad << 3));
#pragma unroll
            for (int i = 0; i < 4; i++)
#pragma unroll
                for (int j = 0; j < 4; j++)
                    acc[i][j] = __builtin_amdgcn_mfma_f32_16x16x32_bf16(
                        af[i], bfr[j], acc[i][j], 0, 0, 0);
            __syncthreads();
        }
    }

    const int eg = (e_gate >= 0) ? e_gate : z;

    if constexpr (MODE == 0 || MODE == 1) {
        bf16* C = (bf16*)Cout + (long)z * out_z;
        const bf16* bb = bias + (long)z * bias_z;
        float gv[4][4];
        if constexpr (MODE == 1) {
#pragma unroll
            for (int i = 0; i < 4; i++)
#pragma unroll
                for (int rg = 0; rg < 4; rg++)
                    gv[i][rg] = gates[(row0 + m0 + wr + i * 16 + quad * 4 + rg) * 8 + eg];
        }
#pragma unroll
        for (int j = 0; j < 4; j++) {
            const int c = (int)n0 + wc + j * 16 + l15;
            const float bv = __bfloat162float(bb[c]);
#pragma unroll
            for (int i = 0; i < 4; i++) {
#pragma unroll
                for (int rg = 0; rg < 4; rg++) {
                    const long r = m0 + wr + i * 16 + quad * 4 + rg;
                    float v = fmaxf(acc[i][j][rg] + bv, 0.f);
                    if constexpr (MODE == 1) v *= gv[i][rg];
                    C[r * ldo + c] = __float2bfloat16(v);
                }
            }
        }
    } else if constexpr (MODE == 2) {
        float* C = (float*)Cout;
#pragma unroll
        for (int i = 0; i < 4; i++) {
#pragma unroll
            for (int rg = 0; rg < 4; rg++) {
                const long r = m0 + wr + i * 16 + quad * 4 + rg;
                const float g = gates[(row0 + r) * 8 + eg];
#pragma unroll
                for (int j = 0; j < 4; j++) {
                    const int c = (int)n0 + wc + j * 16 + l15;
                    const float b3 = __bfloat162float(eb3[eg * O_ + c]);
                    C[r * ldo + c] += acc[i][j][rg] + g * b3;
                }
            }
        }
    }
}

// ---------------------------------------------------------------------------
// 256x256-tile 8-phase GEMM (m201 structure). ROUND-11 BYTE-IDENTICAL
// signature/source (MODE 0/1/4/5 kept instantiated -- rule #19). Wins at
// K>=1024 (hi>=8); at K=512 both this and gemm_bt plateau ~equal (round-15
// measurement) -- no faster L2 structure is available in this harness.
// Round-13 lesson: keep the separate reduce launch (in-kernel last-block
// reduction is a loss). MODE 0/1: z-batched relu(+gate). MODE 4: split-K
// z=8 partials. MODE 5: pair split-K partials (experts 2z,2z+1; K=1024
// via contiguous 1024-col slices of h2 [B][E*H] and ew3t [O][E*H]).
// ---------------------------------------------------------------------------
template <int MODE>
__global__ __launch_bounds__(512, 2)
void gemm256(const bf16* __restrict__ A, const bf16* __restrict__ Bt,
             const bf16* __restrict__ bias, const float* __restrict__ gates,
             void* __restrict__ Cout, const bf16* __restrict__ eb3,
             int lda, int ldb, int ldo, int K,
             long a_z, long b_z, long bias_z, long out_z, long row0) {
    __shared__ __attribute__((aligned(16))) bf16 lds[2][2][256 * 64];

    // T1: bijective XCD swizzle (nwg per z-slice is a multiple of 8 everywhere)
    int bx = blockIdx.x, by = blockIdx.y;
    {
        const int gx = gridDim.x;
        const int nwg = gx * gridDim.y;
        if ((nwg & 7) == 0) {
            int lin = bx + gx * by;
            lin = (lin & 7) * (nwg >> 3) + (lin >> 3);
            bx = lin % gx; by = lin / gx;
        }
    }

    const int tid  = threadIdx.x;
    const int lane = tid & 63;
    const int quad = lane >> 4;
    const int l15  = lane & 15;
    const int w    = tid >> 6;
    const int wm   = w >> 2;
    const int wn   = w & 3;
    const int z    = blockIdx.z;
    const long m0  = (long)by << 8;
    const long n0  = (long)bx << 8;

    const bf16* __restrict__ Az = A + z * a_z;
    const bf16* __restrict__ Bz = Bt + z * b_z;

    f32x4 acc[8][4];
#pragma unroll
    for (int i = 0; i < 8; ++i)
#pragma unroll
        for (int j = 0; j < 4; ++j) acc[i][j] = (f32x4){0.f, 0.f, 0.f, 0.f};

    bf16x8 af[4][2], bv[2][2];

    auto stage = [&](int buf, int mat, int half, int kt) {
        const bf16* __restrict__ G = mat ? Bz : Az;
        const int ld = mat ? ldb : lda;
        const long p0 = mat ? n0 : m0;
#pragma unroll
        for (int l = 0; l < 2; ++l) {
            const int ci = (w << 1) | l;                       // 0..15, wave-uniform
            const int rb = mat ? ((ci >> 2) << 6) + (half << 5) + ((ci & 3) << 3)
                               : ((ci >> 3) << 7) + (half << 6) + ((ci & 7) << 3);
            const int row = rb + (lane >> 3);
            const int cb  = ((lane & 7) << 4) ^ ((row & 7) << 4);  // T2 inverse-swz src
            GLDS(G + (p0 + row) * ld + kt * 64 + (cb >> 1),
                 &lds[buf][mat][rb * 64]);
        }
    };
    auto ldaf = [&](int buf, int qm) {
#pragma unroll
        for (int i = 0; i < 4; ++i) {
            const int r = (wm << 7) + (qm << 6) + (i << 4) + l15;
            const char* p = (const char*)&lds[buf][0][r * 64];
            const int sw = (r & 7) << 4;
#pragma unroll
            for (int s = 0; s < 2; ++s)
                af[i][s] = *(const bf16x8*)(p + (((s << 6) + (quad << 4)) ^ sw));
        }
    };
    auto ldbf = [&](int buf, int qn) {
#pragma unroll
        for (int j = 0; j < 2; ++j) {
            const int r = (wn << 6) + (qn << 5) + (j << 4) + l15;
            const char* p = (const char*)&lds[buf][1][r * 64];
            const int sw = (r & 7) << 4;
#pragma unroll
            for (int s = 0; s < 2; ++s)
                bv[j][s] = *(const bf16x8*)(p + (((s << 6) + (quad << 4)) ^ sw));
        }
    };
    auto mmac = [&](int qm, int qn) {
#pragma unroll
        for (int i = 0; i < 4; ++i)
#pragma unroll
            for (int j = 0; j < 2; ++j)
#pragma unroll
                for (int s = 0; s < 2; ++s)
                    acc[(qm << 2) + i][(qn << 1) + j] =
                        __builtin_amdgcn_mfma_f32_16x16x32_bf16(
                            af[i][s], bv[j][s], acc[(qm << 2) + i][(qn << 1) + j],
                            0, 0, 0);
    };

    const int nt = K >> 6;           // K-tiles (even, >=2 at all call sites)

    // prologue: tile0 full -> buf0; tile1 halves0 -> buf1; guarantee tile0.
    stage(0, 0, 0, 0); stage(0, 0, 1, 0); stage(0, 1, 0, 0); stage(0, 1, 1, 0);
    stage(1, 0, 0, 1); stage(1, 1, 0, 1);
    asm volatile("s_waitcnt vmcnt(4)" ::: "memory");
    BAR();

    const int hi = nt >> 1;
    for (int it = 0; it < hi; ++it) {
        const int t1k = 2 * it + 1, t2k = 2 * it + 2, t3k = 2 * it + 3;
        const bool do2 = t2k < nt, do3 = t3k < nt;
        // P0
        ldaf(0, 0); ldbf(0, 0); stage(1, 0, 1, t1k);
        BAR(); LGKM0();
        __builtin_amdgcn_s_setprio(1); mmac(0, 0); __builtin_amdgcn_s_setprio(0);
        BAR();
        // P1
        ldbf(0, 1); stage(1, 1, 1, t1k);
        BAR(); LGKM0();
        __builtin_amdgcn_s_setprio(1); mmac(0, 1); __builtin_amdgcn_s_setprio(0);
        BAR();
        // P2
        ldaf(0, 1); ldbf(0, 0); if (do2) stage(0, 0, 0, t2k);
        BAR(); LGKM0();
        __builtin_amdgcn_s_setprio(1); mmac(1, 0); __builtin_amdgcn_s_setprio(0);
        BAR();
        // P3
        ldbf(0, 1); if (do2) stage(0, 1, 0, t2k);
        BAR(); LGKM0();
        __builtin_amdgcn_s_setprio(1); mmac(1, 1); __builtin_amdgcn_s_setprio(0);
        if (do2) { asm volatile("s_waitcnt vmcnt(4)" ::: "memory"); }
        else     { asm volatile("s_waitcnt vmcnt(0)" ::: "memory"); }
        BAR();
        // P4
        ldaf(1, 0); ldbf(1, 0); if (do2) stage(0, 0, 1, t2k);
        BAR(); LGKM0();
        __builtin_amdgcn_s_setprio(1); mmac(0, 0); __builtin_amdgcn_s_setprio(0);
        BAR();
        // P5
        ldbf(1, 1); if (do2) stage(0, 1, 1, t2k);
        BAR(); LGKM0();
        __builtin_amdgcn_s_setprio(1); mmac(0, 1); __builtin_amdgcn_s_setprio(0);
        BAR();
        // P6
        ldaf(1, 1); ldbf(1, 0); if (do3) stage(1, 0, 0, t3k);
        BAR(); LGKM0();
        __builtin_amdgcn_s_setprio(1); mmac(1, 0); __builtin_amdgcn_s_setprio(0);
        BAR();
        // P7
        ldbf(1, 1); if (do3) stage(1, 1, 0, t3k);
        BAR(); LGKM0();
        __builtin_amdgcn_s_setprio(1); mmac(1, 1); __builtin_amdgcn_s_setprio(0);
        if (do3) { asm volatile("s_waitcnt vmcnt(4)" ::: "memory"); }
        else     { asm volatile("s_waitcnt vmcnt(0)" ::: "memory"); }
        BAR();
    }

    // ---------------- epilogue (C/D: row=quad*4+reg, col=l15) --------------
    if constexpr (MODE == 0 || MODE == 1) {
        bf16* C = (bf16*)Cout + z * out_z;
        const bf16* bb = bias + z * bias_z;
        float bvv[4];
#pragma unroll
        for (int jg = 0; jg < 4; ++jg)
            bvv[jg] = __bfloat162float(bb[(int)n0 + (wn << 6) + (jg << 4) + l15]);
#pragma unroll
        for (int ig = 0; ig < 8; ++ig) {
#pragma unroll
            for (int rg = 0; rg < 4; ++rg) {
                const long r = m0 + (wm << 7) + (ig << 4) + (quad << 2) + rg;
                float g = 1.f;
                if constexpr (MODE == 1) g = gates[(row0 + r) * 8 + z];
#pragma unroll
                for (int jg = 0; jg < 4; ++jg) {
                    const int c = (int)n0 + (wn << 6) + (jg << 4) + l15;
                    float v = fmaxf(acc[ig][jg][rg] + bvv[jg], 0.f);
                    if constexpr (MODE == 1) v *= g;
                    C[r * ldo + c] = __float2bfloat16(v);
                }
            }
        }
    } else if constexpr (MODE == 4) {  // split-K z=8 partials, plain stores
        float* C = (float*)Cout + z * out_z;
        float b3v[4];
#pragma unroll
        for (int jg = 0; jg < 4; ++jg)
            b3v[jg] = __bfloat162float(eb3[z * O_ + (int)n0 + (wn << 6) + (jg << 4) + l15]);
#pragma unroll
        for (int ig = 0; ig < 8; ++ig) {
#pragma unroll
            for (int rg = 0; rg < 4; ++rg) {
                const long r = m0 + (wm << 7) + (ig << 4) + (quad << 2) + rg;
                const float g = gates[(row0 + r) * 8 + z];
#pragma unroll
                for (int jg = 0; jg < 4; ++jg) {
                    const int c = (int)n0 + (wn << 6) + (jg << 4) + l15;
                    C[r * ldo + c] = acc[ig][jg][rg] + g * b3v[jg];
                }
            }
        }
    } else {  // MODE 5: pair split-K partials (experts 2z, 2z+1)
        float* C = (float*)Cout + z * out_z;
        const int e0 = z << 1;
        float b30[4], b31[4];
#pragma unroll
        for (int jg = 0; jg < 4; ++jg) {
            const int c = (int)n0 + (wn << 6) + (jg << 4) + l15;
            b30[jg] = __bfloat162float(eb3[e0 * O_ + c]);
            b31[jg] = __bfloat162float(eb3[(e0 + 1) * O_ + c]);
        }
#pragma unroll
        for (int ig = 0; ig < 8; ++ig) {
#pragma unroll
            for (int rg = 0; rg < 4; ++rg) {
                const long r = m0 + (wm << 7) + (ig << 4) + (quad << 2) + rg;
                const float g0 = gates[(row0 + r) * 8 + e0];
                const float g1 = gates[(row0 + r) * 8 + e0 + 1];
#pragma unroll
                for (int jg = 0; jg < 4; ++jg) {
                    const int c = (int)n0 + (wn << 6) + (jg << 4) + l15;
                    C[r * ldo + c] = acc[ig][jg][rg] + g0 * b30[jg] + g1 * b31[jg];
                }
            }
        }
    }
}

// ---------------------------------------------------------------------------
__global__ void zero_f32_k(float* __restrict__ p) {
    p[(long)blockIdx.x * 256 + threadIdx.x] = 0.f;
}
__global__ void out_cvt_k(const float* __restrict__ in, void* __restrict__ out,
                          const int* __restrict__ flag) {
    const long i = (long)blockIdx.x * 256 + threadIdx.x;
    if (*flag) ((float*)out)[i] = in[i];
    else       ((bf16*)out)[i] = __float2bfloat16(in[i]);
}
// sum NZ split-K partial buffers [NZ][n] -> out rows [off..off+n)
template <int NZ>
__global__ void reduceN_k(const float* __restrict__ p, void* __restrict__ out,
                          const int* __restrict__ flag, long n, long off) {
    const long i = ((long)blockIdx.x * 256 + threadIdx.x) * 4;
    float4 s = *(const float4*)(p + i);
#pragma unroll
    for (int zz = 1; zz < NZ; ++zz) {
        float4 a = *(const float4*)(p + (long)zz * n + i);
        s.x += a.x; s.y += a.y; s.z += a.z; s.w += a.w;
    }
    if (*flag) {
        *(float4*)((float*)out + off + i) = s;
    } else {
        bf16* o = (bf16*)out + off + i;
        o[0] = __float2bfloat16(s.x); o[1] = __float2bfloat16(s.y);
        o[2] = __float2bfloat16(s.z); o[3] = __float2bfloat16(s.w);
    }
}

// ---------------------------------------------------------------------------
extern "C" void kernel_launch(void* const* d_in, const int* in_sizes, int n_in,
                              void* d_out, int out_size, void* d_ws, size_t ws_size,
                              hipStream_t stream) {
    (void)in_sizes; (void)n_in; (void)out_size;
    const void* x   = d_in[0];
    const void* gw1 = d_in[1];
    const void* gb1 = d_in[2];
    const void* gw2 = d_in[3];
    const void* gb2 = d_in[4];
    const void* gw3 = d_in[5];
    const void* gb3 = d_in[6];
    const void* ew1 = d_in[7];
    const void* eb1 = d_in[8];
    const void* ew2 = d_in[9];
    const void* eb2 = d_in[10];
    const void* ew3 = d_in[11];
    const void* eb3 = d_in[12];

    char* ws = (char*)d_ws;
    size_t off = 0;
    auto alloc = [&](size_t n) { char* p = ws + off; off += (n + 255) & ~(size_t)255; return p; };

    int*  flag  = (int*)alloc(256);
    bf16* xc    = (bf16*)alloc((size_t)B_ * D_ * 2);
    bf16* ew1t  = (bf16*)alloc((size_t)E_ * H_ * D_ * 2);
    bf16* gw1t  = (bf16*)alloc((size_t)256 * 1024 * 2);
    bf16* gw2t  = (bf16*)alloc((size_t)128 * 256 * 2);
    bf16* ew2t  = (bf16*)alloc((size_t)E_ * H_ * H_ * 2);
    bf16* ew3t  = (bf16*)alloc((size_t)E_ * O_ * H_ * 2);
    bf16* eb1c  = (bf16*)alloc((size_t)E_ * H_ * 2);
    bf16* gb1c  = (bf16*)alloc(256 * 2);
    bf16* gb2c  = (bf16*)alloc(128 * 2);
    bf16* gw3c  = (bf16*)alloc(1032 * 2);        // [0..1023]=gw3, [1024..1031]=gb3
    bf16* gb3c  = gw3c + 1024;
    bf16* eb2c  = (bf16*)alloc((size_t)E_ * H_ * 2);
    bf16* eb3c  = (bf16*)alloc((size_t)E_ * O_ * 2);
    float* gates = (float*)alloc((size_t)B_ * 8 * 4);
    bf16* g1    = (bf16*)alloc((size_t)B_ * 256 * 2);

    const size_t smallCore = off;
    // pathPair : h1c [E][BC][H] (64 MiB, reused per chunk) + h2 FULL [B][4096]
    //            (128 MiB); parts4 (64 MiB) ALIASES h1c. (round-11/14 verified)
    // pathChunk: h1c + h2c [BC][4096] + parts8 (round-9 verified fallback).
    const size_t needPair = smallCore + ((size_t)E_ * BC_ * H_ * 2 + 256)
                                      + ((size_t)B_ * E_ * H_ * 2 + 256) + 4096;
    const size_t needChunk = smallCore + ((size_t)E_ * BC_ * H_ * 2 + 256)
                                       + ((size_t)BC_ * E_ * H_ * 2 + 256)
                                       + (8ull * BC_ * O_ * 4 + 256) + 4096;
    const bool pathPair  = ws_size >= needPair;
    const bool pathChunk = ws_size >= needChunk;

    // 1) DEVICE-side dtype detect (element counts are dtype-blind on host)
    detect_k<<<1, 256, 0, stream>>>((const unsigned short*)x, flag);

    // 2) all preprocessing in one launch (ew3t layout per path)
    const bool l3pair = pathPair || pathChunk;
    const long e3zo = l3pair ? (long)H_ : (long)O_ * H_;   // [O][E*H] vs [E][O][H]
    const long e3cs = l3pair ? (long)E_ * H_ : (long)H_;
    preproc_k<<<8487, dim3(32, 8), 0, stream>>>(
        x, xc, gb1, gb2, gw3, gb3, eb1, eb2, eb3,
        gb1c, gb2c, gw3c, gb3c, eb1c, eb2c, eb3c,
        gw1, gw2, ew1, ew2, ew3, gw1t, gw2t, ew1t, ew2t, ew3t,
        e3zo, e3cs, flag);

    // 3) gating: g1 GEMM, then FUSED g2+g3+softmax (one launch)
    gemm_bt<0><<<dim3(2, 128, 1), 256, 0, stream>>>(
        xc, gw1t, gb1c, nullptr, g1, nullptr,
        1024, 1024, 256, 1024, 0, 0, 0, 0, 0, 0, 0, 0, 0);
    gate23_k<<<dim3(128), 256, 0, stream>>>(g1, gw2t, gb2c, gw3c, gates);

    // 4) experts (round-11/14 verified structure)
    if (pathPair) {
        bf16* h1c = (bf16*)alloc((size_t)E_ * BC_ * H_ * 2);     // [E][BC][H]
        bf16* h2  = (bf16*)alloc((size_t)B_ * E_ * H_ * 2);      // [B][4096] full
        float* parts = (float*)h1c;                              // alias (64 MiB)

        for (int ch = 0; ch < B_ / BC_; ch++) {
            const long rb = (long)ch * BC_;
            // L1 chunk (z=e batched, 512 blocks = 2 full rounds)
            gemm256<0><<<dim3(2, BC_ / 256, 8), 512, 0, stream>>>(
                xc + rb * D_, ew1t, eb1c, nullptr, h1c, nullptr,
                D_, D_, H_, D_,
                0, (long)H_ * D_, (long)H_, (long)BC_ * H_, 0);
            // L2 chunk (gates folded) -> FULL h2 rows [rb, rb+BC)
            gemm256<1><<<dim3(2, BC_ / 256, 8), 512, 0, stream>>>(
                h1c, ew2t, eb2c, gates, h2 + rb * (long)E_ * H_, nullptr,
                H_, H_, E_ * H_, H_,
                (long)BC_ * H_, (long)H_ * H_, (long)H_, (long)H_, rb);
        }
        // L3 pair split-K over full B: z=4, K=1024, grid (1,64,4) = 256
        // blocks = 1 round; separate full-grid reduce (round-13 lesson).
        gemm256<5><<<dim3(1, B_ / 256, 4), 512, 0, stream>>>(
            h2, ew3t, nullptr, gates, parts, eb3c,
            E_ * H_, E_ * H_, O_, 1024,
            2L * H_, 2L * H_, 0, (long)B_ * O_, 0);
        reduceN_k<4><<<dim3(B_ * O_ / 1024), 256, 0, stream>>>(
            parts, d_out, flag, (long)B_ * O_, 0L);
    } else if (pathChunk) {
        bf16* h1c = (bf16*)alloc((size_t)E_ * BC_ * H_ * 2);     // [E][BC][H]
        bf16* h2c = (bf16*)alloc((size_t)BC_ * E_ * H_ * 2);     // [BC][E*H]
        float* parts = (float*)alloc(8ull * BC_ * O_ * 4);       // [8][BC][O]

        for (int ch = 0; ch < B_ / BC_; ch++) {
            const long rb = (long)ch * BC_;
            gemm256<0><<<dim3(2, BC_ / 256, 8), 512, 0, stream>>>(
                xc + rb * D_, ew1t, eb1c, nullptr, h1c, nullptr,
                D_, D_, H_, D_,
                0, (long)H_ * D_, (long)H_, (long)BC_ * H_, 0);
            gemm256<1><<<dim3(2, BC_ / 256, 8), 512, 0, stream>>>(
                h1c, ew2t, eb2c, gates, h2c, nullptr,
                H_, H_, E_ * H_, H_,
                (long)BC_ * H_, (long)H_ * H_, (long)H_, (long)H_, rb);
            gemm256<4><<<dim3(1, BC_ / 256, 8), 512, 0, stream>>>(
                h2c, ew3t, nullptr, gates, parts, eb3c,
                E_ * H_, E_ * H_, O_, 512,
                (long)H_, (long)H_, 0, (long)BC_ * O_, rb);
            reduceN_k<8><<<dim3(BC_ * O_ / 1024), 256, 0, stream>>>(
                parts, d_out, flag, (long)BC_ * O_, rb * O_);
        }
    } else {
        bf16* h1s = (bf16*)alloc((size_t)B_ * H_ * 2);
        bf16* h2s = (bf16*)alloc((size_t)B_ * H_ * 2);
        float* oacc = (float*)alloc((size_t)B_ * O_ * 4);
        zero_f32_k<<<dim3(B_ * O_ / 256), 256, 0, stream>>>(oacc);
        for (int e = 0; e < E_; e++) {
            gemm_bt<0><<<dim3(4, 128, 1), 256, 0, stream>>>(
                xc, ew1t + (size_t)e * H_ * D_, eb1c + (size_t)e * H_, nullptr, h1s, nullptr,
                1024, 1024, 512, 1024, 0, 0, 0, 0, 0, 0, 0, 0, 0);
            gemm_bt<1><<<dim3(4, 128, 1), 256, 0, stream>>>(
                h1s, ew2t + (size_t)e * H_ * H_, eb2c + (size_t)e * H_, gates, h2s, nullptr,
                512, 512, 512, 512, 0, 0, 0, 0, e, 0, 0, 0, 0);
            gemm_bt<2><<<dim3(2, 128, 1), 256, 0, stream>>>(
                h2s, ew3t + (size_t)e * O_ * H_, nullptr, gates, oacc, eb3c,
                512, 512, 256, 512, 0, 0, 0, 0, e, 0, 0, 0, 0);
        }
        out_cvt_k<<<dim3(B_ * O_ / 256), 256, 0, stream>>>(oacc, d_out, flag);
    }
}